// Round 1
// baseline (238.872 us; speedup 1.0000x reference)
//
#include <hip/hip_runtime.h>

// Problem constants (fixed by setup_inputs): B=8, S=4096, H=1024
constexpr int Bn  = 8;
constexpr int Sn  = 4096;
constexpr int Nn  = Bn * Sn;      // 32768 labels
constexpr int Hn  = 1024;
constexpr int TPB = 1024;         // one workgroup does the whole scan
constexpr int PER = Nn / TPB;     // 32 labels per thread
constexpr int NW  = TPB / 64;     // 16 waves per block

// Single-block exclusive prefix-sum of (label==0), plus per-example
// "extra" offset (examples whose last label == 1 bump all following
// examples by +1). Writes segment ids as float32 (harness reads d_out
// as one flat float32 buffer; ids <= ~16400 are exact in fp32).
__global__ __launch_bounds__(TPB) void seg_ids_kernel(const int* __restrict__ labels,
                                                      float* __restrict__ out) {
    __shared__ int wave_sums[NW];
    __shared__ int extra_off_sh[Bn];

    const int tid  = threadIdx.x;
    const int lane = tid & 63;
    const int wave = tid >> 6;
    const int base = tid * PER;

    // Load this thread's 32 contiguous labels (int4-vectorized, 16B aligned)
    int inc[PER];
    int sum = 0;
    const int4* l4 = reinterpret_cast<const int4*>(labels + base);
#pragma unroll
    for (int i = 0; i < PER / 4; ++i) {
        int4 v = l4[i];
        inc[4 * i + 0] = (v.x == 0); sum += inc[4 * i + 0];
        inc[4 * i + 1] = (v.y == 0); sum += inc[4 * i + 1];
        inc[4 * i + 2] = (v.z == 0); sum += inc[4 * i + 2];
        inc[4 * i + 3] = (v.w == 0); sum += inc[4 * i + 3];
    }

    // Wave64 inclusive scan of per-thread sums
    int incl = sum;
#pragma unroll
    for (int off = 1; off < 64; off <<= 1) {
        int u = __shfl_up(incl, off, 64);
        if (lane >= off) incl += u;
    }
    if (lane == 63) wave_sums[wave] = incl;

    // Tiny serial job: exclusive scan of the 8 per-example "extra" bits
    if (tid == 0) {
        int acc = 0;
#pragma unroll
        for (int b = 0; b < Bn; ++b) {
            extra_off_sh[b] = acc;
            acc += (labels[b * Sn + Sn - 1] == 1);
        }
    }
    __syncthreads();

    // One wave scans the 16 wave totals (all 64 lanes participate in shfl)
    if (wave == 0) {
        int v = (lane < NW) ? wave_sums[lane] : 0;
#pragma unroll
        for (int off = 1; off < NW; off <<= 1) {
            int u = __shfl_up(v, off, 64);
            if (lane >= off) v += u;
        }
        if (lane < NW) wave_sums[lane] = v;
    }
    __syncthreads();

    // Exclusive prefix for this thread's first element, then serial write-out
    int excl = (wave ? wave_sums[wave - 1] : 0) + (incl - sum);
#pragma unroll
    for (int i = 0; i < PER; ++i) {
        int idx = base + i;
        out[idx] = (float)(excl + extra_off_sh[idx >> 12]);  // idx>>12 == idx / Sn
        excl += inc[i];
    }
}

extern "C" void kernel_launch(void* const* d_in, const int* in_sizes, int n_in,
                              void* d_out, int out_size, void* d_ws, size_t ws_size,
                              hipStream_t stream) {
    const float* seq    = (const float*)d_in[0];  // [B,S,H] fp32
    const int*   labels = (const int*)d_in[1];    // [B,S] int (harness-cast)
    float*       out    = (float*)d_out;

    const size_t feat_elems = (size_t)Nn * Hn;    // 33,554,432

    // Output 0: sent_features == sequence_output.reshape(B*S, H) — pure copy.
    // Memory-bound floor: 268 MB of HBM traffic @ ~6.3 TB/s ≈ 43 us.
    hipMemcpyAsync(out, seq, feat_elems * sizeof(float),
                   hipMemcpyDeviceToDevice, stream);

    // Output 1: 32768 segment ids via single-block scan (~3 us, negligible).
    seg_ids_kernel<<<1, TPB, 0, stream>>>(labels, out + feat_elems);
}